// Round 6
// baseline (282.498 us; speedup 1.0000x reference)
//
#include <hip/hip_runtime.h>
#include <hip/hip_fp16.h>
#include <math.h>

#define N1 10242
#define N2 40962
#define N3 163842

constexpr float SLOPE = 0.2f;
constexpr int TB = 256;
constexpr int MAXNB = 512;

typedef unsigned int u32;

__device__ inline u32 packh2(float a, float b) {
    __half2 h = __floats2half2_rn(a, b);
    return *reinterpret_cast<u32*>(&h);
}
__device__ inline float2 unpackh2(u32 v) {
    __half2 h;
    *reinterpret_cast<u32*>(&h) = v;
    return __half22float2(h);
}

// ---- grid barrier: dedicated counter per instance, sleep-backoff poll, 1 poller/block ----
__device__ inline void gbar(int* cnt, int nb) {
    __syncthreads();
    if (threadIdx.x == 0) {
        __threadfence();  // release: all prior global writes visible at device scope
        atomicAdd(cnt, 1);  // device-scope by default on gfx950
        while (__hip_atomic_load(cnt, __ATOMIC_RELAXED, __HIP_MEMORY_SCOPE_AGENT) < nb)
            __builtin_amdgcn_s_sleep(8);
        __threadfence();  // acquire: see all writes released before the last arrival
    }
    __syncthreads();
}

// ---- block reduce of K doubles via wave butterfly + tiny LDS combine (conflict-free) ----
template <int K>
__device__ inline void block_reduce_write(double* v, double* __restrict__ out_row,
                                          double* shred) {
#pragma unroll
    for (int m = 1; m < 64; m <<= 1) {
#pragma unroll
        for (int k = 0; k < K; ++k) v[k] += __shfl_xor(v[k], m, 64);
    }
    int lane = threadIdx.x & 63, wid = threadIdx.x >> 6;
    __syncthreads();
    if (lane < K) shred[wid * K + lane] = v[lane];
    __syncthreads();
    if (threadIdx.x < K)
        out_row[threadIdx.x] = shred[threadIdx.x] + shred[K + threadIdx.x] +
                               shred[2 * K + threadIdx.x] + shred[3 * K + threadIdx.x];
}

// ---- finalize BN stats from nb partial rows -> ss[2C] = {scale, shift} ----
template <int C>
__device__ inline void finalize_ss(const double* __restrict__ part, int nb, int n,
                                   const float* __restrict__ g, const float* __restrict__ bb,
                                   float* ss, double* red) {
    constexpr int K = 2 * C;
    constexpr int G = TB / K;
    double* tot = red + TB;
    int tid = threadIdx.x;
    double s = 0.0;
    if (tid < G * K) {
        int k = tid % K, i0 = tid / K;
        for (int i = i0; i < nb; i += G) s += part[(size_t)i * K + k];
    }
    red[tid] = s;
    __syncthreads();
    if (tid < K) {
        double t = 0.0;
        for (int j = 0; j < G; ++j) t += red[j * K + tid];
        tot[tid] = t;
    }
    __syncthreads();
    if (tid < C) {
        double mean = tot[tid] / (double)n;
        double var = tot[C + tid] / (double)n - mean * mean;
        if (var < 0.0) var = 0.0;
        float rstd = (float)(1.0 / sqrt(var + 1e-5));
        float sc = g[tid] * rstd;
        ss[tid] = sc;
        ss[C + tid] = bb[tid] - (float)mean * sc;
    }
    __syncthreads();
}

__device__ inline float yv(const float* a, const float* wsm, const float* bsm, int col) {
    return fmaf(a[0], wsm[col * 3 + 0],
           fmaf(a[1], wsm[col * 3 + 1],
           fmaf(a[2], wsm[col * 3 + 2], bsm[col])));
}

// ---- up phase: finalize stats(3) -> BN+LReLU -> 3->21 -> scatter -> fp16 rows + stats ----
template <bool SRC16>
__device__ inline void up_phase(const void* __restrict__ xsrc, int R, int Nn,
                                const double* __restrict__ partIn, int nb, int nprev,
                                const float* __restrict__ g, const float* __restrict__ bb,
                                const float* __restrict__ w, const float* __restrict__ b,
                                const int* __restrict__ top, const int* __restrict__ down,
                                uint2* __restrict__ out, double* __restrict__ partOutRow,
                                float* ss, float* wsm, float* bsm, double* red, double* shred,
                                int gid, int gsz) {
    finalize_ss<3>(partIn, nb, nprev, g, bb, ss, red);
    int tid = threadIdx.x;
    if (tid < 63) wsm[tid] = w[tid];
    if (tid < 21) bsm[tid] = b[tid];
    __syncthreads();
    double v[6] = {0, 0, 0, 0, 0, 0};
    for (int i = gid; i < Nn; i += gsz) {
        auto loadact = [&](int r, float* a) {
            if constexpr (SRC16) {
                uint2 vv = ((const uint2*)xsrc)[r];
                float2 p = unpackh2(vv.x), q = unpackh2(vv.y);
                a[0] = p.x; a[1] = p.y; a[2] = q.x;
            } else {
                const float* xf = (const float*)xsrc;
                a[0] = xf[(size_t)r * 3 + 0];
                a[1] = xf[(size_t)r * 3 + 1];
                a[2] = xf[(size_t)r * 3 + 2];
            }
#pragma unroll
            for (int c = 0; c < 3; ++c) {
                float u = fmaf(a[c], ss[c], ss[3 + c]);
                a[c] = u >= 0.f ? u : SLOPE * u;
            }
        };
        float o0, o1, o2;
        if (i < R) {
            int t = top[i];
            int r = t / 7, jg = t % 7;
            float a[3];
            loadact(r, a);
            o0 = yv(a, wsm, bsm, jg * 3 + 0);
            o1 = yv(a, wsm, bsm, jg * 3 + 1);
            o2 = yv(a, wsm, bsm, jg * 3 + 2);
        } else {
            int k2 = i - R;
            int d0 = down[2 * k2 + 0];
            int d1 = down[2 * k2 + 1];
            int r0 = d0 / 7, j0 = d0 % 7;
            int r1 = d1 / 7, j1 = d1 % 7;
            float a0[3], a1[3];
            loadact(r0, a0);
            loadact(r1, a1);
            float y00 = yv(a0, wsm, bsm, j0 * 3 + 0);
            float y01 = yv(a0, wsm, bsm, j0 * 3 + 1);
            float y02 = yv(a0, wsm, bsm, j0 * 3 + 2);
            float y10 = yv(a1, wsm, bsm, j1 * 3 + 0);
            float y11 = yv(a1, wsm, bsm, j1 * 3 + 1);
            float y12 = yv(a1, wsm, bsm, j1 * 3 + 2);
            // y[down].reshape(-1,3,2).mean(-1): channel-mixing across the row pair
            o0 = 0.5f * (y00 + y01);
            o1 = 0.5f * (y02 + y10);
            o2 = 0.5f * (y11 + y12);
        }
        out[i] = make_uint2(packh2(o0, o1), packh2(o2, 0.f));
        v[0] += o0; v[1] += o1; v[2] += o2;
        v[3] += (double)o0 * o0; v[4] += (double)o1 * o1; v[5] += (double)o2 * o2;
    }
    block_reduce_write<6>(v, partOutRow, shred);
}

// ---- conv phase: finalize stats(CIN) -> BN+LReLU 7-ring conv over fp16 rows (+stats) ----
template <int CIN, int COUT, bool STATS, bool OUT16>
__device__ inline void conv_phase(const void* __restrict__ xsrc, const int* __restrict__ neigh,
                                  const double* __restrict__ partIn, int nb,
                                  const float* __restrict__ g, const float* __restrict__ bb,
                                  const float* __restrict__ w, const float* __restrict__ b,
                                  void* __restrict__ outv, double* __restrict__ partOutRow,
                                  float* ss, float* wsm, float* bsm, double* red, double* shred,
                                  int gid, int gsz) {
    finalize_ss<CIN>(partIn, nb, N3, g, bb, ss, red);
    int tid = threadIdx.x;
    for (int t = tid; t < COUT * 7 * CIN; t += TB) wsm[t] = w[t];
    if (tid < COUT) bsm[tid] = b[tid];
    __syncthreads();
    double v[2 * COUT];
#pragma unroll
    for (int k = 0; k < 2 * COUT; ++k) v[k] = 0.0;
    for (int i = gid; i < N3; i += gsz) {
        float acc[COUT];
#pragma unroll
        for (int o = 0; o < COUT; ++o) acc[o] = bsm[o];
        const int* np = neigh + (size_t)i * 7;
#pragma unroll
        for (int j = 0; j < 7; ++j) {
            int vn = np[j];
            float xv[CIN];
            if constexpr (CIN == 3) {
                uint2 vv = ((const uint2*)xsrc)[vn];
                float2 p = unpackh2(vv.x), q = unpackh2(vv.y);
                xv[0] = p.x; xv[1] = p.y; xv[2] = q.x;
            } else {
                uint4 vv = ((const uint4*)xsrc)[vn];
                float2 p0 = unpackh2(vv.x), p1 = unpackh2(vv.y);
                float2 p2 = unpackh2(vv.z), p3 = unpackh2(vv.w);
                xv[0] = p0.x; xv[1] = p0.y; xv[2] = p1.x; xv[3] = p1.y;
                xv[4] = p2.x; xv[5] = p2.y; xv[6] = p3.x; xv[7] = p3.y;
            }
#pragma unroll
            for (int c = 0; c < CIN; ++c) {
                float t = fmaf(xv[c], ss[c], ss[CIN + c]);
                t = t >= 0.f ? t : SLOPE * t;
#pragma unroll
                for (int o = 0; o < COUT; ++o)
                    acc[o] = fmaf(t, wsm[o * 7 * CIN + j * CIN + c], acc[o]);
            }
        }
        if constexpr (OUT16) {
            uint4 ov;
            ov.x = packh2(acc[0], acc[1]);
            ov.y = packh2(acc[2], acc[3]);
            ov.z = packh2(acc[4], acc[5]);
            ov.w = packh2(acc[6], acc[7]);
            ((uint4*)outv)[i] = ov;
        } else {
            ((float2*)outv)[i] = make_float2(acc[0], acc[1]);
        }
        if constexpr (STATS) {
#pragma unroll
            for (int o = 0; o < COUT; ++o) {
                v[o] += acc[o];
                v[COUT + o] += (double)acc[o] * acc[o];
            }
        }
    }
    if constexpr (STATS) block_reduce_write<2 * COUT>(v, partOutRow, shred);
}

struct Params {
    const float *age, *aw, *ab, *fc_w, *fc_b;
    const float *g_up0, *b_up0, *up0_w, *up0_b;
    const float *g_up1, *b_up1, *up1_w, *up1_b;
    const float *g0, *b0, *c0w, *c0b;
    const float *g1, *b1, *c1w, *c1b;
    const float *g2, *b2, *c2w, *c2b;
    const int *top0, *down0, *top1, *down1, *neigh;
    float *bufA;
    uint2 *up0o, *up1o;
    uint4 *c0o, *c1o;
    float *out;
    double *pP, *pQ;
    int *cnt;
};

__global__ void k_init(int* cnt) {
    if (threadIdx.x < 8) cnt[threadIdx.x] = 0;
}

__global__ __launch_bounds__(TB, 2) void k_all(Params P) {
    const int tid = threadIdx.x;
    const int nb = gridDim.x;
    const int gsz = nb * TB;
    const int gid = blockIdx.x * TB + tid;

    __shared__ float xs[64];
    __shared__ float ss[16];
    __shared__ float wsm[448];
    __shared__ float bsm[24];
    __shared__ double red[TB + 16];
    __shared__ double shred[64];

    // ---- phase 0: fc_age + fc -> bufA (N1,3) fp32, stats(3) -> pP ----
    if (tid < 64) xs[tid] = P.age[0] * P.aw[tid] + P.ab[tid];
    __syncthreads();
    {
        double v[6] = {0, 0, 0, 0, 0, 0};
        for (int i = gid; i < 3 * N1; i += gsz) {
            const float4* wr = (const float4*)(P.fc_w + (size_t)i * 64);
            float acc = 0.f;
#pragma unroll
            for (int q = 0; q < 16; ++q) {
                float4 w4 = wr[q];
                acc = fmaf(w4.x, xs[4 * q + 0], acc);
                acc = fmaf(w4.y, xs[4 * q + 1], acc);
                acc = fmaf(w4.z, xs[4 * q + 2], acc);
                acc = fmaf(w4.w, xs[4 * q + 3], acc);
            }
            float val = acc + P.fc_b[i];
            P.bufA[i] = val;
            double dv = (double)val, dq = dv * dv;
            int c = i % 3;  // static-index accumulators (rule #20)
            if (c == 0)      { v[0] += dv; v[3] += dq; }
            else if (c == 1) { v[1] += dv; v[4] += dq; }
            else             { v[2] += dv; v[5] += dq; }
        }
        block_reduce_write<6>(v, P.pP + (size_t)blockIdx.x * 6, shred);
    }
    gbar(P.cnt + 0, nb);

    // ---- phase 1: up0 N1->N2 (fp32 -> fp16 rows), stats -> pQ ----
    up_phase<false>(P.bufA, N1, N2, P.pP, nb, N1, P.g_up0, P.b_up0, P.up0_w, P.up0_b,
                    P.top0, P.down0, P.up0o, P.pQ + (size_t)blockIdx.x * 6,
                    ss, wsm, bsm, red, shred, gid, gsz);
    gbar(P.cnt + 1, nb);

    // ---- phase 2: up1 N2->N3 (fp16 -> fp16 rows), stats -> pP ----
    up_phase<true>(P.up0o, N2, N3, P.pQ, nb, N2, P.g_up1, P.b_up1, P.up1_w, P.up1_b,
                   P.top1, P.down1, P.up1o, P.pP + (size_t)blockIdx.x * 6,
                   ss, wsm, bsm, red, shred, gid, gsz);
    gbar(P.cnt + 2, nb);

    // ---- phase 3: conv0 (N3,3)h -> (N3,8)h, stats -> pQ ----
    conv_phase<3, 8, true, true>(P.up1o, P.neigh, P.pP, nb, P.g0, P.b0, P.c0w, P.c0b,
                                 P.c0o, P.pQ + (size_t)blockIdx.x * 16,
                                 ss, wsm, bsm, red, shred, gid, gsz);
    gbar(P.cnt + 3, nb);

    // ---- phase 4: conv1 (N3,8)h -> (N3,8)h, stats -> pP ----
    conv_phase<8, 8, true, true>(P.c0o, P.neigh, P.pQ, nb, P.g1, P.b1, P.c1w, P.c1b,
                                 P.c1o, P.pP + (size_t)blockIdx.x * 16,
                                 ss, wsm, bsm, red, shred, gid, gsz);
    gbar(P.cnt + 4, nb);

    // ---- phase 5: conv2 (N3,8)h -> (N3,2) fp32 -> d_out ----
    conv_phase<8, 2, false, false>(P.c1o, P.neigh, P.pP, nb, P.g2, P.b2, P.c2w, P.c2b,
                                   P.out, nullptr, ss, wsm, bsm, red, shred, gid, gsz);
}

extern "C" void kernel_launch(void* const* d_in, const int* in_sizes, int n_in,
                              void* d_out, int out_size, void* d_ws, size_t ws_size,
                              hipStream_t stream) {
    Params P;
    P.age    = (const float*)d_in[0];
    P.aw     = (const float*)d_in[1];
    P.ab     = (const float*)d_in[2];
    P.fc_w   = (const float*)d_in[3];
    P.fc_b   = (const float*)d_in[4];
    P.g_up0  = (const float*)d_in[5];
    P.b_up0  = (const float*)d_in[6];
    P.up0_w  = (const float*)d_in[7];
    P.up0_b  = (const float*)d_in[8];
    P.g_up1  = (const float*)d_in[9];
    P.b_up1  = (const float*)d_in[10];
    P.up1_w  = (const float*)d_in[11];
    P.up1_b  = (const float*)d_in[12];
    P.g0     = (const float*)d_in[13];
    P.b0     = (const float*)d_in[14];
    P.c0w    = (const float*)d_in[15];
    P.c0b    = (const float*)d_in[16];
    P.g1     = (const float*)d_in[17];
    P.b1     = (const float*)d_in[18];
    P.c1w    = (const float*)d_in[19];
    P.c1b    = (const float*)d_in[20];
    P.g2     = (const float*)d_in[21];
    P.b2     = (const float*)d_in[22];
    P.c2w    = (const float*)d_in[23];
    P.c2b    = (const float*)d_in[24];
    P.top0   = (const int*)d_in[25];
    P.down0  = (const int*)d_in[26];
    P.top1   = (const int*)d_in[27];
    P.down1  = (const int*)d_in[28];
    P.neigh  = (const int*)d_in[29];

    char* base = (char*)d_ws;
    P.bufA = (float*)base;                  // (N1,3) fp32
    P.up0o = (uint2*)(base + 0x020000);     // (N2) 4h rows
    P.up1o = (uint2*)(base + 0x080000);     // (N3) 4h rows
    P.c0o  = (uint4*)(base + 0x200000);     // (N3) 8h rows
    P.c1o  = (uint4*)(base + 0x500000);     // (N3) 8h rows
    double* dbase = (double*)(base + 0x800000);
    P.pP  = dbase;                          // MAXNB x 16 doubles
    P.pQ  = dbase + (size_t)MAXNB * 16;
    P.cnt = (int*)(dbase + (size_t)2 * MAXNB * 16);
    P.out = (float*)d_out;

    int maxb = 0;
    hipOccupancyMaxActiveBlocksPerMultiprocessor(&maxb, k_all, TB, 0);
    if (maxb < 1) maxb = 1;
    long long cap = (long long)maxb * 256;
    int grid = (int)(cap > MAXNB ? MAXNB : cap);

    k_init<<<1, 64, 0, stream>>>(P.cnt);
    void* args[] = {&P};
    hipLaunchCooperativeKernel((void*)k_all, dim3(grid), dim3(TB), args, 0, stream);
}

// Round 7
// 174.602 us; speedup vs baseline: 1.6179x; 1.6179x over previous
//
#include <hip/hip_runtime.h>
#include <hip/hip_fp16.h>
#include <math.h>

#define N1 10242
#define N2 40962
#define N3 163842

constexpr float SLOPE = 0.2f;
constexpr int TB = 256;

static inline int cdiv(int a, int b) { return (a + b - 1) / b; }

typedef unsigned int u32;

__device__ inline u32 packh2(float a, float b) {
    __half2 h = __floats2half2_rn(a, b);
    return *reinterpret_cast<u32*>(&h);
}
__device__ inline float2 unpackh2(u32 v) {
    __half2 h;
    *reinterpret_cast<u32*>(&h) = v;
    return __half22float2(h);
}

// ---- block reduce of K doubles via wave butterfly + tiny LDS combine (conflict-free) ----
template <int K>
__device__ void block_reduce_part(double* v, double* __restrict__ part_out, int bid) {
    __shared__ double shred[4 * K];
#pragma unroll
    for (int m = 1; m < 64; m <<= 1) {
#pragma unroll
        for (int k = 0; k < K; ++k) v[k] += __shfl_xor(v[k], m, 64);
    }
    int lane = threadIdx.x & 63, wid = threadIdx.x >> 6;
    if (lane < K) shred[wid * K + lane] = v[lane];
    __syncthreads();
    int tid = threadIdx.x;
    if (tid < K) {
        double t = shred[tid] + shred[K + tid] + shred[2 * K + tid] + shred[3 * K + tid];
        part_out[(size_t)bid * K + tid] = t;
    }
}

// ---- finalize BN stats from nb partial rows -> ss[2C] = {scale, shift} ----
template <int C>
__device__ void finalize_ss(const double* __restrict__ part, int nb, int n,
                            const float* __restrict__ g, const float* __restrict__ bb,
                            float* ss) {
    constexpr int K = 2 * C;
    constexpr int G = TB / K;
    __shared__ double red[TB];
    __shared__ double tot[K];
    int tid = threadIdx.x;
    double s = 0.0;
    if (tid < G * K) {
        int k = tid % K, i0 = tid / K;
        for (int i = i0; i < nb; i += G) s += part[(size_t)i * K + k];
    }
    red[tid] = s;
    __syncthreads();
    if (tid < K) {
        double t = 0.0;
        for (int j = 0; j < G; ++j) t += red[j * K + tid];
        tot[tid] = t;
    }
    __syncthreads();
    if (tid < C) {
        double mean = tot[tid] / (double)n;
        double var = tot[C + tid] / (double)n - mean * mean;
        if (var < 0.0) var = 0.0;
        float rstd = (float)(1.0 / sqrt(var + 1e-5));
        float sc = g[tid] * rstd;
        ss[tid] = sc;
        ss[C + tid] = bb[tid] - (float)mean * sc;
    }
    __syncthreads();
}

// ================= Kernel A: fc_age + fc -> fp32 (N1,3) + stats(3) =================
__global__ void k_fc_stats(const float* __restrict__ age,
                           const float* __restrict__ aw, const float* __restrict__ ab,
                           const float* __restrict__ w, const float* __restrict__ b,
                           float* __restrict__ out, double* __restrict__ part) {
    __shared__ float xs[64];
    int tid = threadIdx.x;
    if (tid < 64) xs[tid] = age[0] * aw[tid] + ab[tid];
    __syncthreads();
    int i = blockIdx.x * TB + tid;
    float val = 0.f;
    bool valid = i < 3 * N1;
    if (valid) {
        const float4* wr = (const float4*)(w + (size_t)i * 64);
        float acc = 0.f;
#pragma unroll
        for (int q = 0; q < 16; ++q) {
            float4 v = wr[q];
            acc = fmaf(v.x, xs[4 * q + 0], acc);
            acc = fmaf(v.y, xs[4 * q + 1], acc);
            acc = fmaf(v.z, xs[4 * q + 2], acc);
            acc = fmaf(v.w, xs[4 * q + 3], acc);
        }
        val = acc + b[i];
        out[i] = val;
    }
    double v[6] = {0, 0, 0, 0, 0, 0};
    if (valid) {
        double dv = (double)val, dq = dv * dv;
        int c = i % 3;  // static-index accumulators (rule #20)
        if (c == 0)      { v[0] = dv; v[3] = dq; }
        else if (c == 1) { v[1] = dv; v[4] = dq; }
        else             { v[2] = dv; v[5] = dq; }
    }
    block_reduce_part<6>(v, part, blockIdx.x);
}

// ================= Kernel B: BN+LReLU + 3->21 linear + scatter -> fp16 rows + stats(3) ====
__device__ inline float yv(const float* a, const float* wsm, const float* bsm, int col) {
    return fmaf(a[0], wsm[col * 3 + 0],
           fmaf(a[1], wsm[col * 3 + 1],
           fmaf(a[2], wsm[col * 3 + 2], bsm[col])));
}

template <bool SRC16>
__global__ void k_up_fused(const void* __restrict__ xsrc, int R, int Nn,
                           const double* __restrict__ part, int nb, int nprev,
                           const float* __restrict__ g, const float* __restrict__ bb,
                           const float* __restrict__ w, const float* __restrict__ b,
                           const int* __restrict__ top, const int* __restrict__ down,
                           uint2* __restrict__ out, double* __restrict__ opart) {
    __shared__ float ss[6];
    __shared__ float wsm[63], bsm[21];
    finalize_ss<3>(part, nb, nprev, g, bb, ss);
    int tid = threadIdx.x;
    if (tid < 63) wsm[tid] = w[tid];
    if (tid < 21) bsm[tid] = b[tid];
    __syncthreads();
    float sc0 = ss[0], sc1 = ss[1], sc2 = ss[2];
    float sh0 = ss[3], sh1 = ss[4], sh2 = ss[5];
    int i = blockIdx.x * TB + tid;
    float o0 = 0.f, o1 = 0.f, o2 = 0.f;
    bool valid = i < Nn;
    if (valid) {
        auto loadact = [&](int r, float* a) {
            if constexpr (SRC16) {
                uint2 vv = ((const uint2*)xsrc)[r];
                float2 p = unpackh2(vv.x), q = unpackh2(vv.y);
                a[0] = p.x; a[1] = p.y; a[2] = q.x;
            } else {
                const float* xf = (const float*)xsrc;
                a[0] = xf[(size_t)r * 3 + 0];
                a[1] = xf[(size_t)r * 3 + 1];
                a[2] = xf[(size_t)r * 3 + 2];
            }
            float u0 = fmaf(a[0], sc0, sh0); a[0] = u0 >= 0.f ? u0 : SLOPE * u0;
            float u1 = fmaf(a[1], sc1, sh1); a[1] = u1 >= 0.f ? u1 : SLOPE * u1;
            float u2 = fmaf(a[2], sc2, sh2); a[2] = u2 >= 0.f ? u2 : SLOPE * u2;
        };
        if (i < R) {
            int t = top[i];
            int r = t / 7, jg = t % 7;
            float a[3];
            loadact(r, a);
            o0 = yv(a, wsm, bsm, jg * 3 + 0);
            o1 = yv(a, wsm, bsm, jg * 3 + 1);
            o2 = yv(a, wsm, bsm, jg * 3 + 2);
        } else {
            int k2 = i - R;
            int d0 = down[2 * k2 + 0];
            int d1 = down[2 * k2 + 1];
            int r0 = d0 / 7, j0 = d0 % 7;
            int r1 = d1 / 7, j1 = d1 % 7;
            float a0[3], a1[3];
            loadact(r0, a0);
            loadact(r1, a1);
            float y00 = yv(a0, wsm, bsm, j0 * 3 + 0);
            float y01 = yv(a0, wsm, bsm, j0 * 3 + 1);
            float y02 = yv(a0, wsm, bsm, j0 * 3 + 2);
            float y10 = yv(a1, wsm, bsm, j1 * 3 + 0);
            float y11 = yv(a1, wsm, bsm, j1 * 3 + 1);
            float y12 = yv(a1, wsm, bsm, j1 * 3 + 2);
            // y[down].reshape(-1,3,2).mean(-1): channel-mixing across the row pair
            o0 = 0.5f * (y00 + y01);
            o1 = 0.5f * (y02 + y10);
            o2 = 0.5f * (y11 + y12);
        }
        out[i] = make_uint2(packh2(o0, o1), packh2(o2, 0.f));
    }
    double v[6] = {0, 0, 0, 0, 0, 0};
    if (valid) {
        v[0] = (double)o0; v[1] = (double)o1; v[2] = (double)o2;
        v[3] = (double)o0 * o0; v[4] = (double)o1 * o1; v[5] = (double)o2 * o2;
    }
    block_reduce_part<6>(v, opart, blockIdx.x);
}

// ======= Kernel C: BN+LReLU + one-ring conv, V=2 vertices/thread, transposed weights ======
template <int CIN, int COUT, bool STATS, bool OUT16>
__global__ void k_conv_fused(const void* __restrict__ xsrc, const int* __restrict__ neigh,
                             const double* __restrict__ part, int nb,
                             const float* __restrict__ g, const float* __restrict__ bb,
                             const float* __restrict__ w, const float* __restrict__ b,
                             void* __restrict__ outv, double* __restrict__ opart) {
    __shared__ float ss[2 * CIN];
    __shared__ alignas(16) float wT[7 * CIN * COUT];   // [(j*CIN+c)*COUT + o]
    __shared__ float bsm[COUT];
    finalize_ss<CIN>(part, nb, N3, g, bb, ss);
    int tid = threadIdx.x;
    for (int t = tid; t < 7 * CIN * COUT; t += TB)
        wT[t] = w[(t % COUT) * (7 * CIN) + t / COUT];
    if (tid < COUT) bsm[tid] = b[tid];
    __syncthreads();

    // hoist BN params to registers
    float sc[CIN], sh[CIN];
#pragma unroll
    for (int c = 0; c < CIN; ++c) { sc[c] = ss[c]; sh[c] = ss[CIN + c]; }

    int v0 = blockIdx.x * (2 * TB) + tid;
    int v1 = v0 + TB;
    bool ok0 = v0 < N3, ok1 = v1 < N3;
    const int* np0 = neigh + (size_t)(ok0 ? v0 : 0) * 7;
    const int* np1 = neigh + (size_t)(ok1 ? v1 : 0) * 7;

    float acc0[COUT], acc1[COUT];
#pragma unroll
    for (int o = 0; o < COUT; ++o) { acc0[o] = bsm[o]; acc1[o] = bsm[o]; }

#pragma unroll
    for (int j = 0; j < 7; ++j) {
        int n0 = np0[j], n1 = np1[j];
        float xa[CIN], xb[CIN];
        if constexpr (CIN == 3) {
            uint2 va = ((const uint2*)xsrc)[n0];
            float2 pa = unpackh2(va.x), qa = unpackh2(va.y);
            xa[0] = pa.x; xa[1] = pa.y; xa[2] = qa.x;
            uint2 vb = ((const uint2*)xsrc)[n1];
            float2 pb = unpackh2(vb.x), qb = unpackh2(vb.y);
            xb[0] = pb.x; xb[1] = pb.y; xb[2] = qb.x;
        } else {
            uint4 va = ((const uint4*)xsrc)[n0];
            float2 a0 = unpackh2(va.x), a1 = unpackh2(va.y), a2 = unpackh2(va.z), a3 = unpackh2(va.w);
            xa[0] = a0.x; xa[1] = a0.y; xa[2] = a1.x; xa[3] = a1.y;
            xa[4] = a2.x; xa[5] = a2.y; xa[6] = a3.x; xa[7] = a3.y;
            uint4 vb = ((const uint4*)xsrc)[n1];
            float2 b0 = unpackh2(vb.x), b1 = unpackh2(vb.y), b2 = unpackh2(vb.z), b3 = unpackh2(vb.w);
            xb[0] = b0.x; xb[1] = b0.y; xb[2] = b1.x; xb[3] = b1.y;
            xb[4] = b2.x; xb[5] = b2.y; xb[6] = b3.x; xb[7] = b3.y;
        }
#pragma unroll
        for (int c = 0; c < CIN; ++c) {
            float t0 = fmaf(xa[c], sc[c], sh[c]); t0 = t0 >= 0.f ? t0 : SLOPE * t0;
            float t1 = fmaf(xb[c], sc[c], sh[c]); t1 = t1 >= 0.f ? t1 : SLOPE * t1;
            const float* wr = &wT[(j * CIN + c) * COUT];
            if constexpr (COUT == 8) {
                float4 wa = ((const float4*)wr)[0];
                float4 wbv = ((const float4*)wr)[1];
                acc0[0] = fmaf(t0, wa.x, acc0[0]);  acc1[0] = fmaf(t1, wa.x, acc1[0]);
                acc0[1] = fmaf(t0, wa.y, acc0[1]);  acc1[1] = fmaf(t1, wa.y, acc1[1]);
                acc0[2] = fmaf(t0, wa.z, acc0[2]);  acc1[2] = fmaf(t1, wa.z, acc1[2]);
                acc0[3] = fmaf(t0, wa.w, acc0[3]);  acc1[3] = fmaf(t1, wa.w, acc1[3]);
                acc0[4] = fmaf(t0, wbv.x, acc0[4]); acc1[4] = fmaf(t1, wbv.x, acc1[4]);
                acc0[5] = fmaf(t0, wbv.y, acc0[5]); acc1[5] = fmaf(t1, wbv.y, acc1[5]);
                acc0[6] = fmaf(t0, wbv.z, acc0[6]); acc1[6] = fmaf(t1, wbv.z, acc1[6]);
                acc0[7] = fmaf(t0, wbv.w, acc0[7]); acc1[7] = fmaf(t1, wbv.w, acc1[7]);
            } else {
                float2 wp = ((const float2*)wr)[0];
                acc0[0] = fmaf(t0, wp.x, acc0[0]);  acc1[0] = fmaf(t1, wp.x, acc1[0]);
                acc0[1] = fmaf(t0, wp.y, acc0[1]);  acc1[1] = fmaf(t1, wp.y, acc1[1]);
            }
        }
    }

    if (ok0) {
        if constexpr (OUT16) {
            uint4 ov;
            ov.x = packh2(acc0[0], acc0[1]); ov.y = packh2(acc0[2], acc0[3]);
            ov.z = packh2(acc0[4], acc0[5]); ov.w = packh2(acc0[6], acc0[7]);
            ((uint4*)outv)[v0] = ov;
        } else {
            ((float2*)outv)[v0] = make_float2(acc0[0], acc0[1]);
        }
    }
    if (ok1) {
        if constexpr (OUT16) {
            uint4 ov;
            ov.x = packh2(acc1[0], acc1[1]); ov.y = packh2(acc1[2], acc1[3]);
            ov.z = packh2(acc1[4], acc1[5]); ov.w = packh2(acc1[6], acc1[7]);
            ((uint4*)outv)[v1] = ov;
        } else {
            ((float2*)outv)[v1] = make_float2(acc1[0], acc1[1]);
        }
    }

    if constexpr (STATS) {
        double v[2 * COUT];
#pragma unroll
        for (int o = 0; o < COUT; ++o) {
            double s = 0.0, q = 0.0;
            if (ok0) { s += acc0[o]; q += (double)acc0[o] * acc0[o]; }
            if (ok1) { s += acc1[o]; q += (double)acc1[o] * acc1[o]; }
            v[o] = s;
            v[COUT + o] = q;
        }
        block_reduce_part<2 * COUT>(v, opart, blockIdx.x);
    }
}

extern "C" void kernel_launch(void* const* d_in, const int* in_sizes, int n_in,
                              void* d_out, int out_size, void* d_ws, size_t ws_size,
                              hipStream_t stream) {
    const float* age      = (const float*)d_in[0];
    const float* fc_age_w = (const float*)d_in[1];
    const float* fc_age_b = (const float*)d_in[2];
    const float* fc_w     = (const float*)d_in[3];
    const float* fc_b     = (const float*)d_in[4];
    const float* bn_up0_g = (const float*)d_in[5];
    const float* bn_up0_b = (const float*)d_in[6];
    const float* up0_w    = (const float*)d_in[7];
    const float* up0_b    = (const float*)d_in[8];
    const float* bn_up1_g = (const float*)d_in[9];
    const float* bn_up1_b = (const float*)d_in[10];
    const float* up1_w    = (const float*)d_in[11];
    const float* up1_b    = (const float*)d_in[12];
    const float* bn0_g    = (const float*)d_in[13];
    const float* bn0_b    = (const float*)d_in[14];
    const float* conv0_w  = (const float*)d_in[15];
    const float* conv0_b  = (const float*)d_in[16];
    const float* bn1_g    = (const float*)d_in[17];
    const float* bn1_b    = (const float*)d_in[18];
    const float* conv1_w  = (const float*)d_in[19];
    const float* conv1_b  = (const float*)d_in[20];
    const float* bn2_g    = (const float*)d_in[21];
    const float* bn2_b    = (const float*)d_in[22];
    const float* conv2_w  = (const float*)d_in[23];
    const float* conv2_b  = (const float*)d_in[24];
    const int* up_top0    = (const int*)d_in[25];
    const int* up_down0   = (const int*)d_in[26];
    const int* up_top1    = (const int*)d_in[27];
    const int* up_down1   = (const int*)d_in[28];
    const int* neigh      = (const int*)d_in[29];

    // workspace layout (byte offsets, all 16B-aligned)
    char* base = (char*)d_ws;
    float* bufA = (float*)base;                        // (N1,3) fp32
    uint2* up0o = (uint2*)(base + 0x020000);           // (N2) 4h rows
    uint2* up1o = (uint2*)(base + 0x080000);           // (N3) 4h rows
    uint4* c0o  = (uint4*)(base + 0x200000);           // (N3) 8h rows
    uint4* c1o  = (uint4*)(base + 0x500000);           // (N3) 8h rows
    double* dbase  = (double*)(base + 0x800000);
    double* partA  = dbase;                 // 121*6
    double* partB0 = partA + 1024;          // 161*6
    double* partB1 = partB0 + 1024;         // 641*6
    double* partC0 = partB1 + 4096;         // 321*16
    double* partC1 = partC0 + 10752;        // 321*16

    const int nbA  = cdiv(3 * N1, TB);  // 121
    const int nbB0 = cdiv(N2, TB);      // 161
    const int nbB1 = cdiv(N3, TB);      // 641
    const int nbC  = cdiv(N3, 2 * TB);  // 321

    // 1) fc_age + fc -> bufA (N1,3) fp32, stats -> partA
    k_fc_stats<<<nbA, TB, 0, stream>>>(age, fc_age_w, fc_age_b, fc_w, fc_b, bufA, partA);

    // 2) up0: N1 -> N2 (fp32 -> fp16 rows), finalize partA, emit partB0
    k_up_fused<false><<<nbB0, TB, 0, stream>>>(bufA, N1, N2, partA, nbA, N1,
                                               bn_up0_g, bn_up0_b, up0_w, up0_b,
                                               up_top0, up_down0, up0o, partB0);

    // 3) up1: N2 -> N3 (fp16 -> fp16 rows), finalize partB0, emit partB1
    k_up_fused<true><<<nbB1, TB, 0, stream>>>(up0o, N2, N3, partB0, nbB0, N2,
                                              bn_up1_g, bn_up1_b, up1_w, up1_b,
                                              up_top1, up_down1, up1o, partB1);

    // 4) conv0: (N3,3)h -> (N3,8)h, finalize partB1, emit partC0
    k_conv_fused<3, 8, true, true><<<nbC, TB, 0, stream>>>(up1o, neigh, partB1, nbB1,
                                                           bn0_g, bn0_b, conv0_w, conv0_b,
                                                           c0o, partC0);

    // 5) conv1: (N3,8)h -> (N3,8)h, finalize partC0, emit partC1
    k_conv_fused<8, 8, true, true><<<nbC, TB, 0, stream>>>(c0o, neigh, partC0, nbC,
                                                           bn1_g, bn1_b, conv1_w, conv1_b,
                                                           c1o, partC1);

    // 6) conv2: (N3,8)h -> (N3,2) fp32 d_out, finalize partC1
    k_conv_fused<8, 2, false, false><<<nbC, TB, 0, stream>>>(c1o, neigh, partC1, nbC,
                                                             bn2_g, bn2_b, conv2_w, conv2_b,
                                                             (float*)d_out, nullptr);
}

// Round 8
// 126.267 us; speedup vs baseline: 2.2373x; 1.3828x over previous
//
#include <hip/hip_runtime.h>
#include <hip/hip_fp16.h>
#include <math.h>

#define N1 10242
#define N2 40962
#define N3 163842

constexpr float SLOPE = 0.2f;
constexpr int TB = 256;

static inline int cdiv(int a, int b) { return (a + b - 1) / b; }

typedef unsigned int u32;

__device__ inline u32 packh2(float a, float b) {
    __half2 h = __floats2half2_rn(a, b);
    return *reinterpret_cast<u32*>(&h);
}
__device__ inline float2 unpackh2(u32 v) {
    __half2 h;
    *reinterpret_cast<u32*>(&h) = v;
    return __half22float2(h);
}

// ---- block reduce of K doubles via wave butterfly + tiny LDS combine (conflict-free) ----
template <int K>
__device__ void block_reduce_part(double* v, double* __restrict__ part_out, int bid) {
    __shared__ double shred[4 * K];
#pragma unroll
    for (int m = 1; m < 64; m <<= 1) {
#pragma unroll
        for (int k = 0; k < K; ++k) v[k] += __shfl_xor(v[k], m, 64);
    }
    int lane = threadIdx.x & 63, wid = threadIdx.x >> 6;
    if (lane < K) shred[wid * K + lane] = v[lane];
    __syncthreads();
    int tid = threadIdx.x;
    if (tid < K) {
        double t = shred[tid] + shred[K + tid] + shred[2 * K + tid] + shred[3 * K + tid];
        part_out[(size_t)bid * K + tid] = t;
    }
}

// ---- finalize BN stats from nb partial rows -> ss[2C] = {scale, shift} ----
template <int C>
__device__ void finalize_ss(const double* __restrict__ part, int nb, int n,
                            const float* __restrict__ g, const float* __restrict__ bb,
                            float* ss) {
    constexpr int K = 2 * C;
    constexpr int G = TB / K;
    __shared__ double red[TB];
    __shared__ double tot[K];
    int tid = threadIdx.x;
    double s = 0.0;
    if (tid < G * K) {
        int k = tid % K, i0 = tid / K;
        for (int i = i0; i < nb; i += G) s += part[(size_t)i * K + k];
    }
    red[tid] = s;
    __syncthreads();
    if (tid < K) {
        double t = 0.0;
        for (int j = 0; j < G; ++j) t += red[j * K + tid];
        tot[tid] = t;
    }
    __syncthreads();
    if (tid < C) {
        double mean = tot[tid] / (double)n;
        double var = tot[C + tid] / (double)n - mean * mean;
        if (var < 0.0) var = 0.0;
        float rstd = (float)(1.0 / sqrt(var + 1e-5));
        float sc = g[tid] * rstd;
        ss[tid] = sc;
        ss[C + tid] = bb[tid] - (float)mean * sc;
    }
    __syncthreads();
}

// ================= Kernel A: fc_age + fc -> fp32 (N1,3) + stats(3) =================
__global__ void k_fc_stats(const float* __restrict__ age,
                           const float* __restrict__ aw, const float* __restrict__ ab,
                           const float* __restrict__ w, const float* __restrict__ b,
                           float* __restrict__ out, double* __restrict__ part) {
    __shared__ float xs[64];
    int tid = threadIdx.x;
    if (tid < 64) xs[tid] = age[0] * aw[tid] + ab[tid];
    __syncthreads();
    int i = blockIdx.x * TB + tid;
    float val = 0.f;
    bool valid = i < 3 * N1;
    if (valid) {
        const float4* wr = (const float4*)(w + (size_t)i * 64);
        float acc = 0.f;
#pragma unroll
        for (int q = 0; q < 16; ++q) {
            float4 v = wr[q];
            acc = fmaf(v.x, xs[4 * q + 0], acc);
            acc = fmaf(v.y, xs[4 * q + 1], acc);
            acc = fmaf(v.z, xs[4 * q + 2], acc);
            acc = fmaf(v.w, xs[4 * q + 3], acc);
        }
        val = acc + b[i];
        out[i] = val;
    }
    double v[6] = {0, 0, 0, 0, 0, 0};
    if (valid) {
        double dv = (double)val, dq = dv * dv;
        int c = i % 3;  // static-index accumulators (rule #20)
        if (c == 0)      { v[0] = dv; v[3] = dq; }
        else if (c == 1) { v[1] = dv; v[4] = dq; }
        else             { v[2] = dv; v[5] = dq; }
    }
    block_reduce_part<6>(v, part, blockIdx.x);
}

// ================= Kernel B: BN+LReLU + 3->21 linear + scatter -> fp16 rows + stats(3) ====
__device__ inline float yv(const float* a, const float* wsm, const float* bsm, int col) {
    return fmaf(a[0], wsm[col * 3 + 0],
           fmaf(a[1], wsm[col * 3 + 1],
           fmaf(a[2], wsm[col * 3 + 2], bsm[col])));
}

template <bool SRC16>
__global__ void k_up_fused(const void* __restrict__ xsrc, int R, int Nn,
                           const double* __restrict__ part, int nb, int nprev,
                           const float* __restrict__ g, const float* __restrict__ bb,
                           const float* __restrict__ w, const float* __restrict__ b,
                           const int* __restrict__ top, const int* __restrict__ down,
                           uint2* __restrict__ out, double* __restrict__ opart) {
    __shared__ float ss[6];
    __shared__ float wsm[63], bsm[21];
    finalize_ss<3>(part, nb, nprev, g, bb, ss);
    int tid = threadIdx.x;
    if (tid < 63) wsm[tid] = w[tid];
    if (tid < 21) bsm[tid] = b[tid];
    __syncthreads();
    float sc0 = ss[0], sc1 = ss[1], sc2 = ss[2];
    float sh0 = ss[3], sh1 = ss[4], sh2 = ss[5];
    int i = blockIdx.x * TB + tid;
    float o0 = 0.f, o1 = 0.f, o2 = 0.f;
    bool valid = i < Nn;
    if (valid) {
        auto loadact = [&](int r, float* a) {
            if constexpr (SRC16) {
                uint2 vv = ((const uint2*)xsrc)[r];
                float2 p = unpackh2(vv.x), q = unpackh2(vv.y);
                a[0] = p.x; a[1] = p.y; a[2] = q.x;
            } else {
                const float* xf = (const float*)xsrc;
                a[0] = xf[(size_t)r * 3 + 0];
                a[1] = xf[(size_t)r * 3 + 1];
                a[2] = xf[(size_t)r * 3 + 2];
            }
            float u0 = fmaf(a[0], sc0, sh0); a[0] = u0 >= 0.f ? u0 : SLOPE * u0;
            float u1 = fmaf(a[1], sc1, sh1); a[1] = u1 >= 0.f ? u1 : SLOPE * u1;
            float u2 = fmaf(a[2], sc2, sh2); a[2] = u2 >= 0.f ? u2 : SLOPE * u2;
        };
        if (i < R) {
            int t = top[i];
            int r = t / 7, jg = t % 7;
            float a[3];
            loadact(r, a);
            o0 = yv(a, wsm, bsm, jg * 3 + 0);
            o1 = yv(a, wsm, bsm, jg * 3 + 1);
            o2 = yv(a, wsm, bsm, jg * 3 + 2);
        } else {
            int k2 = i - R;
            int d0 = down[2 * k2 + 0];
            int d1 = down[2 * k2 + 1];
            int r0 = d0 / 7, j0 = d0 % 7;
            int r1 = d1 / 7, j1 = d1 % 7;
            float a0[3], a1[3];
            loadact(r0, a0);
            loadact(r1, a1);
            float y00 = yv(a0, wsm, bsm, j0 * 3 + 0);
            float y01 = yv(a0, wsm, bsm, j0 * 3 + 1);
            float y02 = yv(a0, wsm, bsm, j0 * 3 + 2);
            float y10 = yv(a1, wsm, bsm, j1 * 3 + 0);
            float y11 = yv(a1, wsm, bsm, j1 * 3 + 1);
            float y12 = yv(a1, wsm, bsm, j1 * 3 + 2);
            // y[down].reshape(-1,3,2).mean(-1): channel-mixing across the row pair
            o0 = 0.5f * (y00 + y01);
            o1 = 0.5f * (y02 + y10);
            o2 = 0.5f * (y11 + y12);
        }
        out[i] = make_uint2(packh2(o0, o1), packh2(o2, 0.f));
    }
    double v[6] = {0, 0, 0, 0, 0, 0};
    if (valid) {
        v[0] = (double)o0; v[1] = (double)o1; v[2] = (double)o2;
        v[3] = (double)o0 * o0; v[4] = (double)o1 * o1; v[5] = (double)o2 * o2;
    }
    block_reduce_part<6>(v, opart, blockIdx.x);
}

// ======= Kernel C: one-ring conv, 2 THREADS PER VERTEX (even: j=0..3, odd: j=4..6) =======
// grid covers 2*N3 threads; pair combines via __shfl_xor(1); even writes low 8B, odd high.
template <int CIN, int COUT, bool STATS, bool OUT16>
__global__ void k_conv_tpv(const void* __restrict__ xsrc, const int* __restrict__ neigh,
                           const double* __restrict__ part, int nb,
                           const float* __restrict__ g, const float* __restrict__ bb,
                           const float* __restrict__ w, const float* __restrict__ b,
                           void* __restrict__ outv, double* __restrict__ opart) {
    __shared__ float ss[2 * CIN];
    __shared__ float wsm[COUT * 7 * CIN];
    __shared__ float bsm[COUT];
    finalize_ss<CIN>(part, nb, N3, g, bb, ss);
    int tid = threadIdx.x;
    for (int t = tid; t < COUT * 7 * CIN; t += TB) wsm[t] = w[t];
    if (tid < COUT) bsm[tid] = b[tid];
    __syncthreads();

    float sc[CIN], sh[CIN];
#pragma unroll
    for (int c = 0; c < CIN; ++c) { sc[c] = ss[c]; sh[c] = ss[CIN + c]; }

    int gidx = blockIdx.x * TB + tid;
    int vtx = gidx >> 1, half = gidx & 1;
    bool valid = vtx < N3;

    float acc[COUT];
#pragma unroll
    for (int o = 0; o < COUT; ++o) acc[o] = (valid && half == 0) ? bsm[o] : 0.f;

    if (valid) {
        const int* np = neigh + (size_t)vtx * 7;
#pragma unroll
        for (int k = 0; k < 4; ++k) {
            int jj = half * 4 + k;   // even: 0..3, odd: 4..7(7 skipped)
            if (jj < 7) {
                int vn = np[jj];
                float xv[CIN];
                if constexpr (CIN == 3) {
                    uint2 vv = ((const uint2*)xsrc)[vn];
                    float2 p = unpackh2(vv.x), q = unpackh2(vv.y);
                    xv[0] = p.x; xv[1] = p.y; xv[2] = q.x;
                } else {
                    uint4 vv = ((const uint4*)xsrc)[vn];
                    float2 p0 = unpackh2(vv.x), p1 = unpackh2(vv.y);
                    float2 p2 = unpackh2(vv.z), p3 = unpackh2(vv.w);
                    xv[0] = p0.x; xv[1] = p0.y; xv[2] = p1.x; xv[3] = p1.y;
                    xv[4] = p2.x; xv[5] = p2.y; xv[6] = p3.x; xv[7] = p3.y;
                }
#pragma unroll
                for (int c = 0; c < CIN; ++c) {
                    float t = fmaf(xv[c], sc[c], sh[c]);
                    t = t >= 0.f ? t : SLOPE * t;
#pragma unroll
                    for (int o = 0; o < COUT; ++o)
                        acc[o] = fmaf(t, wsm[o * 7 * CIN + jj * CIN + c], acc[o]);
                }
            }
        }
    }

    // pair combine: both threads end with the full per-vertex result
#pragma unroll
    for (int o = 0; o < COUT; ++o) acc[o] += __shfl_xor(acc[o], 1, 64);

    if (valid) {
        if constexpr (OUT16) {
            // per-thread 8B store: byte addr = gidx*8 = vtx*16 + half*8 (coalesced)
            uint2 ov = (half == 0)
                ? make_uint2(packh2(acc[0], acc[1]), packh2(acc[2], acc[3]))
                : make_uint2(packh2(acc[4], acc[5]), packh2(acc[6], acc[7]));
            ((uint2*)outv)[gidx] = ov;
        } else {
            // COUT == 2 fp32: float addr = gidx = vtx*2 + half (coalesced)
            ((float*)outv)[gidx] = (half == 0) ? acc[0] : acc[1];
        }
    }

    if constexpr (STATS) {
        double v[2 * COUT];
#pragma unroll
        for (int o = 0; o < COUT; ++o) {
            double t = (valid && half == 0) ? (double)acc[o] : 0.0;  // count each vertex once
            v[o] = t;
            v[COUT + o] = t * t;
        }
        block_reduce_part<2 * COUT>(v, opart, blockIdx.x);
    }
}

extern "C" void kernel_launch(void* const* d_in, const int* in_sizes, int n_in,
                              void* d_out, int out_size, void* d_ws, size_t ws_size,
                              hipStream_t stream) {
    const float* age      = (const float*)d_in[0];
    const float* fc_age_w = (const float*)d_in[1];
    const float* fc_age_b = (const float*)d_in[2];
    const float* fc_w     = (const float*)d_in[3];
    const float* fc_b     = (const float*)d_in[4];
    const float* bn_up0_g = (const float*)d_in[5];
    const float* bn_up0_b = (const float*)d_in[6];
    const float* up0_w    = (const float*)d_in[7];
    const float* up0_b    = (const float*)d_in[8];
    const float* bn_up1_g = (const float*)d_in[9];
    const float* bn_up1_b = (const float*)d_in[10];
    const float* up1_w    = (const float*)d_in[11];
    const float* up1_b    = (const float*)d_in[12];
    const float* bn0_g    = (const float*)d_in[13];
    const float* bn0_b    = (const float*)d_in[14];
    const float* conv0_w  = (const float*)d_in[15];
    const float* conv0_b  = (const float*)d_in[16];
    const float* bn1_g    = (const float*)d_in[17];
    const float* bn1_b    = (const float*)d_in[18];
    const float* conv1_w  = (const float*)d_in[19];
    const float* conv1_b  = (const float*)d_in[20];
    const float* bn2_g    = (const float*)d_in[21];
    const float* bn2_b    = (const float*)d_in[22];
    const float* conv2_w  = (const float*)d_in[23];
    const float* conv2_b  = (const float*)d_in[24];
    const int* up_top0    = (const int*)d_in[25];
    const int* up_down0   = (const int*)d_in[26];
    const int* up_top1    = (const int*)d_in[27];
    const int* up_down1   = (const int*)d_in[28];
    const int* neigh      = (const int*)d_in[29];

    // workspace layout (byte offsets, all 16B-aligned)
    char* base = (char*)d_ws;
    float* bufA = (float*)base;                        // (N1,3) fp32
    uint2* up0o = (uint2*)(base + 0x020000);           // (N2) 4h rows
    uint2* up1o = (uint2*)(base + 0x080000);           // (N3) 4h rows
    uint4* c0o  = (uint4*)(base + 0x200000);           // (N3) 8h rows
    uint4* c1o  = (uint4*)(base + 0x500000);           // (N3) 8h rows
    double* dbase  = (double*)(base + 0x800000);
    double* partA  = dbase;                 // 121*6
    double* partB0 = partA + 1024;          // 161*6
    double* partB1 = partB0 + 1024;         // 641*6
    double* partC0 = partB1 + 4096;         // 1281*16
    double* partC1 = partC0 + 20992;        // 1281*16

    const int nbA  = cdiv(3 * N1, TB);     // 121
    const int nbB0 = cdiv(N2, TB);         // 161
    const int nbB1 = cdiv(N3, TB);         // 641
    const int nbC  = cdiv(2 * N3, TB);     // 1281 (2 threads per vertex)

    // 1) fc_age + fc -> bufA (N1,3) fp32, stats -> partA
    k_fc_stats<<<nbA, TB, 0, stream>>>(age, fc_age_w, fc_age_b, fc_w, fc_b, bufA, partA);

    // 2) up0: N1 -> N2 (fp32 -> fp16 rows), finalize partA, emit partB0
    k_up_fused<false><<<nbB0, TB, 0, stream>>>(bufA, N1, N2, partA, nbA, N1,
                                               bn_up0_g, bn_up0_b, up0_w, up0_b,
                                               up_top0, up_down0, up0o, partB0);

    // 3) up1: N2 -> N3 (fp16 -> fp16 rows), finalize partB0, emit partB1
    k_up_fused<true><<<nbB1, TB, 0, stream>>>(up0o, N2, N3, partB0, nbB0, N2,
                                              bn_up1_g, bn_up1_b, up1_w, up1_b,
                                              up_top1, up_down1, up1o, partB1);

    // 4) conv0: (N3,3)h -> (N3,8)h, finalize partB1, emit partC0
    k_conv_tpv<3, 8, true, true><<<nbC, TB, 0, stream>>>(up1o, neigh, partB1, nbB1,
                                                         bn0_g, bn0_b, conv0_w, conv0_b,
                                                         c0o, partC0);

    // 5) conv1: (N3,8)h -> (N3,8)h, finalize partC0, emit partC1
    k_conv_tpv<8, 8, true, true><<<nbC, TB, 0, stream>>>(c0o, neigh, partC0, nbC,
                                                         bn1_g, bn1_b, conv1_w, conv1_b,
                                                         c1o, partC1);

    // 6) conv2: (N3,8)h -> (N3,2) fp32 d_out, finalize partC1
    k_conv_tpv<8, 2, false, false><<<nbC, TB, 0, stream>>>(c1o, neigh, partC1, nbC,
                                                           bn2_g, bn2_b, conv2_w, conv2_b,
                                                           (float*)d_out, nullptr);
}

// Round 9
// 87.418 us; speedup vs baseline: 3.2316x; 1.4444x over previous
//
#include <hip/hip_runtime.h>
#include <hip/hip_fp16.h>
#include <math.h>

#define N1 10242
#define N2 40962
#define N3 163842

constexpr float SLOPE = 0.2f;
constexpr int TB = 256;

static inline int cdiv(int a, int b) { return (a + b - 1) / b; }

typedef unsigned int u32;

__device__ inline u32 packh2(float a, float b) {
    __half2 h = __floats2half2_rn(a, b);
    return *reinterpret_cast<u32*>(&h);
}
__device__ inline float2 unpackh2(u32 v) {
    __half2 h;
    *reinterpret_cast<u32*>(&h) = v;
    return __half22float2(h);
}

// ---- block reduce of K doubles via wave butterfly + tiny LDS combine (conflict-free) ----
template <int K>
__device__ void block_reduce_part(double* v, double* __restrict__ part_out, int bid) {
    __shared__ double shred[4 * K];
#pragma unroll
    for (int m = 1; m < 64; m <<= 1) {
#pragma unroll
        for (int k = 0; k < K; ++k) v[k] += __shfl_xor(v[k], m, 64);
    }
    int lane = threadIdx.x & 63, wid = threadIdx.x >> 6;
    if (lane < K) shred[wid * K + lane] = v[lane];
    __syncthreads();
    int tid = threadIdx.x;
    if (tid < K) {
        double t = shred[tid] + shred[K + tid] + shred[2 * K + tid] + shred[3 * K + tid];
        part_out[(size_t)bid * K + tid] = t;
    }
}

// ---- finalize BN stats from nb partial rows -> ss[2C] = {scale, shift} ----
template <int C>
__device__ void finalize_ss(const double* __restrict__ part, int nb, int n,
                            const float* __restrict__ g, const float* __restrict__ bb,
                            float* ss) {
    constexpr int K = 2 * C;
    constexpr int G = TB / K;
    __shared__ double red[TB];
    __shared__ double tot[K];
    int tid = threadIdx.x;
    double s = 0.0;
    if (tid < G * K) {
        int k = tid % K, i0 = tid / K;
        for (int i = i0; i < nb; i += G) s += part[(size_t)i * K + k];
    }
    red[tid] = s;
    __syncthreads();
    if (tid < K) {
        double t = 0.0;
        for (int j = 0; j < G; ++j) t += red[j * K + tid];
        tot[tid] = t;
    }
    __syncthreads();
    if (tid < C) {
        double mean = tot[tid] / (double)n;
        double var = tot[C + tid] / (double)n - mean * mean;
        if (var < 0.0) var = 0.0;
        float rstd = (float)(1.0 / sqrt(var + 1e-5));
        float sc = g[tid] * rstd;
        ss[tid] = sc;
        ss[C + tid] = bb[tid] - (float)mean * sc;
    }
    __syncthreads();
}

// ================= Kernel A: fc_age + fc -> fp32 (N1,3) + stats(3) =================
__global__ void k_fc_stats(const float* __restrict__ age,
                           const float* __restrict__ aw, const float* __restrict__ ab,
                           const float* __restrict__ w, const float* __restrict__ b,
                           float* __restrict__ out, double* __restrict__ part) {
    __shared__ float xs[64];
    int tid = threadIdx.x;
    if (tid < 64) xs[tid] = age[0] * aw[tid] + ab[tid];
    __syncthreads();
    int i = blockIdx.x * TB + tid;
    float val = 0.f;
    bool valid = i < 3 * N1;
    if (valid) {
        const float4* wr = (const float4*)(w + (size_t)i * 64);
        float acc = 0.f;
#pragma unroll
        for (int q = 0; q < 16; ++q) {
            float4 v = wr[q];
            acc = fmaf(v.x, xs[4 * q + 0], acc);
            acc = fmaf(v.y, xs[4 * q + 1], acc);
            acc = fmaf(v.z, xs[4 * q + 2], acc);
            acc = fmaf(v.w, xs[4 * q + 3], acc);
        }
        val = acc + b[i];
        out[i] = val;
    }
    double v[6] = {0, 0, 0, 0, 0, 0};
    if (valid) {
        double dv = (double)val, dq = dv * dv;
        int c = i % 3;  // static-index accumulators (rule #20)
        if (c == 0)      { v[0] = dv; v[3] = dq; }
        else if (c == 1) { v[1] = dv; v[4] = dq; }
        else             { v[2] = dv; v[5] = dq; }
    }
    block_reduce_part<6>(v, part, blockIdx.x);
}

// ================= Kernel B: BN+LReLU + 3->21 linear + scatter -> fp16 rows + stats(3) ====
// up weights: thread-varying column index -> keep LDS staging here (small: 30 reads/thread)
__device__ inline float yv(const float* a, const float* wsm, const float* bsm, int col) {
    return fmaf(a[0], wsm[col * 3 + 0],
           fmaf(a[1], wsm[col * 3 + 1],
           fmaf(a[2], wsm[col * 3 + 2], bsm[col])));
}

template <bool SRC16>
__global__ void k_up_fused(const void* __restrict__ xsrc, int R, int Nn,
                           const double* __restrict__ part, int nb, int nprev,
                           const float* __restrict__ g, const float* __restrict__ bb,
                           const float* __restrict__ w, const float* __restrict__ b,
                           const int* __restrict__ top, const int* __restrict__ down,
                           uint2* __restrict__ out, double* __restrict__ opart) {
    __shared__ float ss[6];
    __shared__ float wsm[63], bsm[21];
    finalize_ss<3>(part, nb, nprev, g, bb, ss);
    int tid = threadIdx.x;
    if (tid < 63) wsm[tid] = w[tid];
    if (tid < 21) bsm[tid] = b[tid];
    __syncthreads();
    float sc0 = ss[0], sc1 = ss[1], sc2 = ss[2];
    float sh0 = ss[3], sh1 = ss[4], sh2 = ss[5];
    int i = blockIdx.x * TB + tid;
    float o0 = 0.f, o1 = 0.f, o2 = 0.f;
    bool valid = i < Nn;
    if (valid) {
        auto loadact = [&](int r, float* a) {
            if constexpr (SRC16) {
                uint2 vv = ((const uint2*)xsrc)[r];
                float2 p = unpackh2(vv.x), q = unpackh2(vv.y);
                a[0] = p.x; a[1] = p.y; a[2] = q.x;
            } else {
                const float* xf = (const float*)xsrc;
                a[0] = xf[(size_t)r * 3 + 0];
                a[1] = xf[(size_t)r * 3 + 1];
                a[2] = xf[(size_t)r * 3 + 2];
            }
            float u0 = fmaf(a[0], sc0, sh0); a[0] = u0 >= 0.f ? u0 : SLOPE * u0;
            float u1 = fmaf(a[1], sc1, sh1); a[1] = u1 >= 0.f ? u1 : SLOPE * u1;
            float u2 = fmaf(a[2], sc2, sh2); a[2] = u2 >= 0.f ? u2 : SLOPE * u2;
        };
        if (i < R) {
            int t = top[i];
            int r = t / 7, jg = t % 7;
            float a[3];
            loadact(r, a);
            o0 = yv(a, wsm, bsm, jg * 3 + 0);
            o1 = yv(a, wsm, bsm, jg * 3 + 1);
            o2 = yv(a, wsm, bsm, jg * 3 + 2);
        } else {
            int k2 = i - R;
            int d0 = down[2 * k2 + 0];
            int d1 = down[2 * k2 + 1];
            int r0 = d0 / 7, j0 = d0 % 7;
            int r1 = d1 / 7, j1 = d1 % 7;
            float a0[3], a1[3];
            loadact(r0, a0);
            loadact(r1, a1);
            float y00 = yv(a0, wsm, bsm, j0 * 3 + 0);
            float y01 = yv(a0, wsm, bsm, j0 * 3 + 1);
            float y02 = yv(a0, wsm, bsm, j0 * 3 + 2);
            float y10 = yv(a1, wsm, bsm, j1 * 3 + 0);
            float y11 = yv(a1, wsm, bsm, j1 * 3 + 1);
            float y12 = yv(a1, wsm, bsm, j1 * 3 + 2);
            // y[down].reshape(-1,3,2).mean(-1): channel-mixing across the row pair
            o0 = 0.5f * (y00 + y01);
            o1 = 0.5f * (y02 + y10);
            o2 = 0.5f * (y11 + y12);
        }
        out[i] = make_uint2(packh2(o0, o1), packh2(o2, 0.f));
    }
    double v[6] = {0, 0, 0, 0, 0, 0};
    if (valid) {
        v[0] = (double)o0; v[1] = (double)o1; v[2] = (double)o2;
        v[3] = (double)o0 * o0; v[4] = (double)o1 * o1; v[5] = (double)o2 * o2;
    }
    block_reduce_part<6>(v, opart, blockIdx.x);
}

// ======= Kernel C: one-ring conv; weights via SCALAR path (uniform global, const idx) =====
// No LDS in the inner loop: w[o*7C+j*C+c] / b[o] are wave-uniform with compile-time
// indices -> s_load into SGPRs (constant cache). All 7 gathers issued before compute.
template <int CIN, int COUT, bool STATS, bool OUT16>
__global__ void k_conv_sreg(const void* __restrict__ xsrc, const int* __restrict__ neigh,
                            const double* __restrict__ part, int nb,
                            const float* __restrict__ g, const float* __restrict__ bb,
                            const float* __restrict__ w, const float* __restrict__ b,
                            void* __restrict__ outv, double* __restrict__ opart) {
    __shared__ float ss[2 * CIN];
    finalize_ss<CIN>(part, nb, N3, g, bb, ss);
    int tid = threadIdx.x;

    // BN params -> registers (uniform per block)
    float sc[CIN], sh[CIN];
#pragma unroll
    for (int c = 0; c < CIN; ++c) { sc[c] = ss[c]; sh[c] = ss[CIN + c]; }

    int i = blockIdx.x * TB + tid;
    bool valid = i < N3;

    float acc[COUT];
#pragma unroll
    for (int o = 0; o < COUT; ++o) acc[o] = b[o];   // uniform -> s_load

    if (valid) {
        const int* np = neigh + (size_t)i * 7;
        int vn[7];
#pragma unroll
        for (int j = 0; j < 7; ++j) vn[j] = np[j];   // 7 index loads in flight

        if constexpr (CIN == 3) {
            uint2 rows[7];
#pragma unroll
            for (int j = 0; j < 7; ++j) rows[j] = ((const uint2*)xsrc)[vn[j]];  // 7 gathers in flight
#pragma unroll
            for (int j = 0; j < 7; ++j) {
                float2 p = unpackh2(rows[j].x), q = unpackh2(rows[j].y);
                float xv[3] = {p.x, p.y, q.x};
#pragma unroll
                for (int c = 0; c < 3; ++c) {
                    float t = fmaf(xv[c], sc[c], sh[c]);
                    t = t >= 0.f ? t : SLOPE * t;
#pragma unroll
                    for (int o = 0; o < COUT; ++o)
                        acc[o] = fmaf(t, w[o * 21 + j * 3 + c], acc[o]);  // SGPR operand
                }
            }
        } else {
            uint4 rows[7];
#pragma unroll
            for (int j = 0; j < 7; ++j) rows[j] = ((const uint4*)xsrc)[vn[j]];  // 7 gathers in flight
#pragma unroll
            for (int j = 0; j < 7; ++j) {
                float2 p0 = unpackh2(rows[j].x), p1 = unpackh2(rows[j].y);
                float2 p2 = unpackh2(rows[j].z), p3 = unpackh2(rows[j].w);
                float xv[8] = {p0.x, p0.y, p1.x, p1.y, p2.x, p2.y, p3.x, p3.y};
#pragma unroll
                for (int c = 0; c < 8; ++c) {
                    float t = fmaf(xv[c], sc[c], sh[c]);
                    t = t >= 0.f ? t : SLOPE * t;
#pragma unroll
                    for (int o = 0; o < COUT; ++o)
                        acc[o] = fmaf(t, w[o * 56 + j * 8 + c], acc[o]);  // SGPR operand
                }
            }
        }

        if constexpr (OUT16) {
            uint4 ov;
            ov.x = packh2(acc[0], acc[1]); ov.y = packh2(acc[2], acc[3]);
            ov.z = packh2(acc[4], acc[5]); ov.w = packh2(acc[6], acc[7]);
            ((uint4*)outv)[i] = ov;
        } else {
            ((float2*)outv)[i] = make_float2(acc[0], acc[1]);
        }
    }

    if constexpr (STATS) {
        double v[2 * COUT];
#pragma unroll
        for (int o = 0; o < COUT; ++o) {
            double t = valid ? (double)acc[o] : 0.0;
            v[o] = t;
            v[COUT + o] = t * t;
        }
        block_reduce_part<2 * COUT>(v, opart, blockIdx.x);
    }
}

extern "C" void kernel_launch(void* const* d_in, const int* in_sizes, int n_in,
                              void* d_out, int out_size, void* d_ws, size_t ws_size,
                              hipStream_t stream) {
    const float* age      = (const float*)d_in[0];
    const float* fc_age_w = (const float*)d_in[1];
    const float* fc_age_b = (const float*)d_in[2];
    const float* fc_w     = (const float*)d_in[3];
    const float* fc_b     = (const float*)d_in[4];
    const float* bn_up0_g = (const float*)d_in[5];
    const float* bn_up0_b = (const float*)d_in[6];
    const float* up0_w    = (const float*)d_in[7];
    const float* up0_b    = (const float*)d_in[8];
    const float* bn_up1_g = (const float*)d_in[9];
    const float* bn_up1_b = (const float*)d_in[10];
    const float* up1_w    = (const float*)d_in[11];
    const float* up1_b    = (const float*)d_in[12];
    const float* bn0_g    = (const float*)d_in[13];
    const float* bn0_b    = (const float*)d_in[14];
    const float* conv0_w  = (const float*)d_in[15];
    const float* conv0_b  = (const float*)d_in[16];
    const float* bn1_g    = (const float*)d_in[17];
    const float* bn1_b    = (const float*)d_in[18];
    const float* conv1_w  = (const float*)d_in[19];
    const float* conv1_b  = (const float*)d_in[20];
    const float* bn2_g    = (const float*)d_in[21];
    const float* bn2_b    = (const float*)d_in[22];
    const float* conv2_w  = (const float*)d_in[23];
    const float* conv2_b  = (const float*)d_in[24];
    const int* up_top0    = (const int*)d_in[25];
    const int* up_down0   = (const int*)d_in[26];
    const int* up_top1    = (const int*)d_in[27];
    const int* up_down1   = (const int*)d_in[28];
    const int* neigh      = (const int*)d_in[29];

    // workspace layout (byte offsets, all 16B-aligned)
    char* base = (char*)d_ws;
    float* bufA = (float*)base;                        // (N1,3) fp32
    uint2* up0o = (uint2*)(base + 0x020000);           // (N2) 4h rows
    uint2* up1o = (uint2*)(base + 0x080000);           // (N3) 4h rows
    uint4* c0o  = (uint4*)(base + 0x200000);           // (N3) 8h rows
    uint4* c1o  = (uint4*)(base + 0x500000);           // (N3) 8h rows
    double* dbase  = (double*)(base + 0x800000);
    double* partA  = dbase;                 // 121*6
    double* partB0 = partA + 1024;          // 161*6
    double* partB1 = partB0 + 1024;         // 641*6
    double* partC0 = partB1 + 4096;         // 641*16
    double* partC1 = partC0 + 10752;        // 641*16

    const int nbA  = cdiv(3 * N1, TB);  // 121
    const int nbB0 = cdiv(N2, TB);      // 161
    const int nbB1 = cdiv(N3, TB);      // 641
    const int nbC  = cdiv(N3, TB);      // 641

    // 1) fc_age + fc -> bufA (N1,3) fp32, stats -> partA
    k_fc_stats<<<nbA, TB, 0, stream>>>(age, fc_age_w, fc_age_b, fc_w, fc_b, bufA, partA);

    // 2) up0: N1 -> N2 (fp32 -> fp16 rows), finalize partA, emit partB0
    k_up_fused<false><<<nbB0, TB, 0, stream>>>(bufA, N1, N2, partA, nbA, N1,
                                               bn_up0_g, bn_up0_b, up0_w, up0_b,
                                               up_top0, up_down0, up0o, partB0);

    // 3) up1: N2 -> N3 (fp16 -> fp16 rows), finalize partB0, emit partB1
    k_up_fused<true><<<nbB1, TB, 0, stream>>>(up0o, N2, N3, partB0, nbB0, N2,
                                              bn_up1_g, bn_up1_b, up1_w, up1_b,
                                              up_top1, up_down1, up1o, partB1);

    // 4) conv0: (N3,3)h -> (N3,8)h, finalize partB1, emit partC0
    k_conv_sreg<3, 8, true, true><<<nbC, TB, 0, stream>>>(up1o, neigh, partB1, nbB1,
                                                          bn0_g, bn0_b, conv0_w, conv0_b,
                                                          c0o, partC0);

    // 5) conv1: (N3,8)h -> (N3,8)h, finalize partC0, emit partC1
    k_conv_sreg<8, 8, true, true><<<nbC, TB, 0, stream>>>(c0o, neigh, partC0, nbC,
                                                          bn1_g, bn1_b, conv1_w, conv1_b,
                                                          c1o, partC1);

    // 6) conv2: (N3,8)h -> (N3,2) fp32 d_out, finalize partC1
    k_conv_sreg<8, 2, false, false><<<nbC, TB, 0, stream>>>(c1o, neigh, partC1, nbC,
                                                            bn2_g, bn2_b, conv2_w, conv2_b,
                                                            (float*)d_out, nullptr);
}